// Round 4
// baseline (918.353 us; speedup 1.0000x reference)
//
#include <hip/hip_runtime.h>
#include <hip/hip_bf16.h>
#include <stdint.h>

typedef unsigned short u16;
typedef __bf16 bf16x8 __attribute__((ext_vector_type(8)));
typedef unsigned short u16x8 __attribute__((ext_vector_type(8)));
typedef float f32x16 __attribute__((ext_vector_type(16)));

__device__ __forceinline__ float bf2f(u16 h) {
  union { uint32_t u; float f; } x;
  x.u = ((uint32_t)h) << 16;
  return x.f;
}
__device__ __forceinline__ u16 f2bf(float f) {
  union { float f; uint32_t u; } x;
  x.f = f;
  uint32_t r = x.u + 0x7FFFu + ((x.u >> 16) & 1u);  // round-to-nearest-even
  return (u16)(r >> 16);
}

// async global->LDS, 16B per lane. LDS dest must be wave-uniform base + lane*16.
__device__ __forceinline__ void gload_lds16(const u16* g, u16* l) {
  __builtin_amdgcn_global_load_lds(
      (const __attribute__((address_space(1))) uint32_t*)g,
      (__attribute__((address_space(3))) uint32_t*)l, 16, 0, 0);
}

// One fused fp32->bf16 convert for x, W_qkv, W_o. Counts are 8-elem chunks.
__global__ __launch_bounds__(256) void cvt_all(
    const float* __restrict__ x, const float* __restrict__ w1,
    const float* __restrict__ w2, u16* __restrict__ xb,
    u16* __restrict__ w1b, u16* __restrict__ w2b, int n1, int n2, int n3) {
  int i = blockIdx.x * 256 + threadIdx.x;
  const float* src;
  u16* dst;
  int j = i;
  if (i < n1) { src = x; dst = xb; }
  else if (i < n1 + n2) { src = w1; dst = w1b; j = i - n1; }
  else if (i < n1 + n2 + n3) { src = w2; dst = w2b; j = i - n1 - n2; }
  else return;
  const float4* p = (const float4*)src + (size_t)j * 2;
  float4 a = p[0], b = p[1];
  u16x8 o;
  o[0] = f2bf(a.x); o[1] = f2bf(a.y); o[2] = f2bf(a.z); o[3] = f2bf(a.w);
  o[4] = f2bf(b.x); o[5] = f2bf(b.y); o[6] = f2bf(b.z); o[7] = f2bf(b.w);
  ((u16x8*)dst)[j] = o;
}

// C[z][m,n] = epi( scale * sum_k A[z][m,k] * B[z][n,k] )
// EPI: 0 plain; 1 exp + fused row-sum atomicAdd into rs; 2 divide by rs[row].
// bf16 in, OT out, fp32 accum. 256 thr (2x2 waves of 64x64), tile 128x128,
// BK=64, MFMA 32x32x16 bf16 (2x2 tiles/wave). LDS chunk-XOR swizzle keeps the
// ds_read_b128 pattern at the m134 baseline (8 lanes per 4-bank window).
template <typename OT, int EPI>
__global__ __launch_bounds__(256) void gemm_bt(
    const u16* __restrict__ A, int lda, long zsA,
    const u16* __restrict__ B, int ldb, long zsB,
    OT* __restrict__ C, int ldc, long zsC,
    int K, float scale, float* __restrict__ rs) {
  const int z = blockIdx.z;
  A += (long)z * zsA;
  B += (long)z * zsB;
  C += (long)z * zsC;
  if constexpr (EPI != 0) rs += (long)z * 4096;  // batch-local rows, S = 4096

  __shared__ __align__(16) u16 As[2 * 128 * 32];  // [s][row][32k]
  __shared__ __align__(16) u16 Bs[2 * 128 * 32];
  const int tid  = threadIdx.x;
  const int m0   = blockIdx.y * 128;
  const int n0   = blockIdx.x * 128;
  const int wave = tid >> 6;
  const int lane = tid & 63;
  const int wm   = (wave >> 1) * 64;
  const int wn   = (wave & 1) * 64;
  const int r31  = lane & 31;
  const int hi   = lane >> 5;

  f32x16 acc[2][2];
#pragma unroll
  for (int i = 0; i < 2; ++i)
#pragma unroll
    for (int j = 0; j < 2; ++j)
#pragma unroll
      for (int g = 0; g < 16; ++g) acc[i][j][g] = 0.f;

  // Staging: per stage s, tile row-major [128][32]. Thread t stages 16B:
  // row = t>>2 (+64), phys chunk = t&3; SOURCE chunk is XOR-swizzled so
  // logical chunk c lives at phys c ^ ((row>>1)&3). (row+64 keeps same swizzle.)
  const int cs = (((tid & 3) ^ ((tid >> 3) & 3))) * 8;  // swizzled src col (elems)
  const u16* gA0 = A + (size_t)(m0 + (tid >> 2)) * lda + cs;
  const u16* gA1 = A + (size_t)(m0 + 64 + (tid >> 2)) * lda + cs;
  const u16* gB0 = B + (size_t)(n0 + (tid >> 2)) * ldb + cs;
  const u16* gB1 = B + (size_t)(n0 + 64 + (tid >> 2)) * ldb + cs;
  u16* lA0 = As + tid * 8;
  u16* lA1 = As + (256 + tid) * 8;
  u16* lB0 = Bs + tid * 8;
  u16* lB1 = Bs + (256 + tid) * 8;

  // Reader: logical chunk for k-step kk is kk*2+hi; phys = logical ^ ((r31>>1)&3).
  const int sw  = (r31 >> 1) & 3;
  const int ck0 = ((0 + hi) ^ sw) * 8;  // kk=0
  const int ck1 = ((2 + hi) ^ sw) * 8;  // kk=1

  for (int k0 = 0; k0 < K; k0 += 64) {
    __syncthreads();  // previous iter's LDS reads done before overwrite
#pragma unroll
    for (int s = 0; s < 2; ++s) {
      gload_lds16(gA0 + k0 + s * 32, lA0 + s * 4096);
      gload_lds16(gA1 + k0 + s * 32, lA1 + s * 4096);
      gload_lds16(gB0 + k0 + s * 32, lB0 + s * 4096);
      gload_lds16(gB1 + k0 + s * 32, lB1 + s * 4096);
    }
    __syncthreads();  // staging landed

#pragma unroll
    for (int s = 0; s < 2; ++s) {
      u16x8 a[2][2], b[2][2];  // [tile][kk]
#pragma unroll
      for (int t = 0; t < 2; ++t) {
        const u16* baseA = As + s * 4096 + (wm + t * 32 + r31) * 32;
        const u16* baseB = Bs + s * 4096 + (wn + t * 32 + r31) * 32;
        a[t][0] = *(const u16x8*)(baseA + ck0);
        a[t][1] = *(const u16x8*)(baseA + ck1);
        b[t][0] = *(const u16x8*)(baseB + ck0);
        b[t][1] = *(const u16x8*)(baseB + ck1);
      }
#pragma unroll
      for (int ti = 0; ti < 2; ++ti)
#pragma unroll
        for (int tj = 0; tj < 2; ++tj) {
          acc[ti][tj] = __builtin_amdgcn_mfma_f32_32x32x16_bf16(
              __builtin_bit_cast(bf16x8, a[ti][0]),
              __builtin_bit_cast(bf16x8, b[tj][0]), acc[ti][tj], 0, 0, 0);
          acc[ti][tj] = __builtin_amdgcn_mfma_f32_32x32x16_bf16(
              __builtin_bit_cast(bf16x8, a[ti][1]),
              __builtin_bit_cast(bf16x8, b[tj][1]), acc[ti][tj], 0, 0, 0);
        }
    }
  }

  // C/D layout (m74/m101-verified): col = lane&31, row = (g&3)+8*(g>>2)+4*hi
  const int colbase = n0 + wn + r31;
#pragma unroll
  for (int ti = 0; ti < 2; ++ti) {
#pragma unroll
    for (int g = 0; g < 16; ++g) {
      const int row = m0 + wm + ti * 32 + (g & 3) + 8 * (g >> 2) + 4 * hi;
      float mul = scale;
      if constexpr (EPI == 2) mul = scale / rs[row];
      float v0 = acc[ti][0][g] * mul;
      float v1 = acc[ti][1][g] * mul;
      if constexpr (EPI == 1) { v0 = __expf(v0); v1 = __expf(v1); }
      const size_t ro = (size_t)row * ldc;
      if constexpr (__is_same(OT, float)) {
        C[ro + colbase]      = v0;
        C[ro + colbase + 32] = v1;
      } else {
        C[ro + colbase]      = f2bf(v0);
        C[ro + colbase + 32] = f2bf(v1);
      }
      if constexpr (EPI == 1) {
        float ps = v0 + v1;  // this lane's 2 cols of this row
#pragma unroll
        for (int o = 1; o <= 16; o <<= 1) ps += __shfl_xor(ps, o, 64);
        if (r31 == 0) atomicAdd(&rs[row], ps);  // 2 lanes (hi=0/1), 2 rows
      }
    }
  }
}

// Vt[z][d, s] = V[z][s, d].
__global__ __launch_bounds__(256) void transpose_v(
    const u16* __restrict__ V, int ldv, long zsV,
    u16* __restrict__ Vt, int ldt, long zsT) {
  const int z = blockIdx.z;
  V  += (long)z * zsV;
  Vt += (long)z * zsT;
  __shared__ u16 T[64][65];
  const int d0 = blockIdx.x * 64;
  const int s0 = blockIdx.y * 64;
  const int tid = threadIdx.x;
  const int c = tid & 63;
  const int rbase = (tid >> 6) * 16;
#pragma unroll
  for (int r = 0; r < 16; ++r)
    T[rbase + r][c] = V[(size_t)(s0 + rbase + r) * ldv + d0 + c];
  __syncthreads();
#pragma unroll
  for (int r = 0; r < 16; ++r)
    Vt[(size_t)(d0 + rbase + r) * ldt + s0 + c] = T[c][rbase + r];
}

extern "C" void kernel_launch(void* const* d_in, const int* in_sizes, int n_in,
                              void* d_out, int out_size, void* d_ws, size_t ws_size,
                              hipStream_t stream) {
  const float* x    = (const float*)d_in[0];  // [B*S, D] fp32
  const float* Wqkv = (const float*)d_in[1];  // [3D, D]  fp32
  const float* Wo   = (const float*)d_in[2];  // [D, D]   fp32
  float* out = (float*)d_out;                 // [B*S, D] fp32

  const int Bn = 4, S = 4096, D = 1024;
  const int M = Bn * S;  // 16384
  const int E = 3 * D;   // 3072
  const long SE = (long)S * E, SS = (long)S * S, DS = (long)D * S, SD = (long)S * D;

  const size_t need4 = 310378496;  // 296 MB -> batched grid.z=4 path
  const int nb = (ws_size >= need4) ? 4 : 1;

  char* ws = (char*)d_ws;
  size_t off = 0;
  u16* qkv = (u16*)(ws + off);  off += (size_t)M * E * 2;        // 96 MB
  u16* Sb  = (u16*)(ws + off);  off += (size_t)nb * S * S * 2;   // nb*32 MB
  u16* Vt  = (u16*)(ws + off);  off += (size_t)nb * D * S * 2;   // nb*8 MB
  u16* xb  = (u16*)(ws + off);  off += (size_t)M * D * 2;        // 32 MB
  u16* attn = xb;                 // xb dead after QKV proj
  u16* Wqkvb = (u16*)(ws + off); off += (size_t)E * D * 2;       // 6 MB
  u16* Wob   = (u16*)(ws + off); off += (size_t)D * D * 2;       // 2 MB
  // rowsum [nb][4096] fp32 aliases Wqkvb (dead after QKV gemm; memset after).
  float* rs = (float*)Wqkvb;

  // 0) fp32 -> bf16 converts (fused)
  const int n1 = M * D / 8, n2 = E * D / 8, n3 = D * D / 8;
  cvt_all<<<(n1 + n2 + n3 + 255) / 256, 256, 0, stream>>>(
      x, Wqkv, Wo, xb, Wqkvb, Wob, n1, n2, n3);

  // 1) QKV projection: qkv = xb @ Wqkvb^T   [16384 x 3072]
  gemm_bt<u16, 0><<<dim3(E / 128, M / 128, 1), 256, 0, stream>>>(
      xb, D, 0, Wqkvb, D, 0, qkv, E, 0, D, 1.0f, nullptr);

  const float scl = 0.03125f;  // 1/sqrt(1024)
  if (nb == 4) {
    hipMemsetAsync(rs, 0, (size_t)4 * S * sizeof(float), stream);
    // 2) P = exp(Q K^T / 32) unnormalized; fused row-sums -> rs (atomics)
    gemm_bt<u16, 1><<<dim3(S / 128, S / 128, 4), 256, 0, stream>>>(
        qkv, E, SE, qkv + D, E, SE, Sb, S, SS, D, scl, rs);
    // 3) Vt = V^T
    transpose_v<<<dim3(D / 64, S / 64, 4), 256, 0, stream>>>(
        qkv + 2 * D, E, SE, Vt, S, DS);
    // 4) attn = (P @ V) / rs
    gemm_bt<u16, 2><<<dim3(D / 128, S / 128, 4), 256, 0, stream>>>(
        Sb, S, SS, Vt, S, DS, attn, D, SD, S, 1.0f, rs);
  } else {
    for (int b = 0; b < Bn; ++b) {
      const u16* Qb = qkv + (size_t)b * SE;
      hipMemsetAsync(rs, 0, (size_t)S * sizeof(float), stream);
      gemm_bt<u16, 1><<<dim3(S / 128, S / 128, 1), 256, 0, stream>>>(
          Qb, E, 0, Qb + D, E, 0, Sb, S, 0, D, scl, rs);
      transpose_v<<<dim3(D / 64, S / 64, 1), 256, 0, stream>>>(
          Qb + 2 * D, E, 0, Vt, S, 0);
      gemm_bt<u16, 2><<<dim3(D / 128, S / 128, 1), 256, 0, stream>>>(
          Sb, S, 0, Vt, S, 0, attn + (size_t)b * SD, D, 0, S, 1.0f, rs);
    }
  }
  // 5) out = attn @ Wo^T  [16384 x 1024] -> fp32
  gemm_bt<float, 0><<<dim3(D / 128, M / 128, 1), 256, 0, stream>>>(
      attn, D, 0, Wob, D, 0, out, D, 0, D, 1.0f, nullptr);
}

// Round 5
// 874.328 us; speedup vs baseline: 1.0504x; 1.0504x over previous
//
#include <hip/hip_runtime.h>
#include <hip/hip_bf16.h>
#include <stdint.h>

typedef unsigned short u16;
typedef __bf16 bf16x8 __attribute__((ext_vector_type(8)));
typedef unsigned short u16x8 __attribute__((ext_vector_type(8)));
typedef float f32x4 __attribute__((ext_vector_type(4)));

__device__ __forceinline__ float bf2f(u16 h) {
  union { uint32_t u; float f; } x;
  x.u = ((uint32_t)h) << 16;
  return x.f;
}
__device__ __forceinline__ u16 f2bf(float f) {
  union { float f; uint32_t u; } x;
  x.f = f;
  uint32_t r = x.u + 0x7FFFu + ((x.u >> 16) & 1u);  // round-to-nearest-even
  return (u16)(r >> 16);
}

// async global->LDS, 16B per lane. LDS dest must be wave-uniform base + lane*16.
__device__ __forceinline__ void gload_lds16(const u16* g, u16* l) {
  __builtin_amdgcn_global_load_lds(
      (const __attribute__((address_space(1))) uint32_t*)g,
      (__attribute__((address_space(3))) uint32_t*)l, 16, 0, 0);
}

// One fused fp32->bf16 convert for x, W_qkv, W_o. Counts are 8-elem chunks.
__global__ __launch_bounds__(256) void cvt_all(
    const float* __restrict__ x, const float* __restrict__ w1,
    const float* __restrict__ w2, u16* __restrict__ xb,
    u16* __restrict__ w1b, u16* __restrict__ w2b, int n1, int n2, int n3) {
  int i = blockIdx.x * 256 + threadIdx.x;
  const float* src;
  u16* dst;
  int j = i;
  if (i < n1) { src = x; dst = xb; }
  else if (i < n1 + n2) { src = w1; dst = w1b; j = i - n1; }
  else if (i < n1 + n2 + n3) { src = w2; dst = w2b; j = i - n1 - n2; }
  else return;
  const float4* p = (const float4*)src + (size_t)j * 2;
  float4 a = p[0], b = p[1];
  u16x8 o;
  o[0] = f2bf(a.x); o[1] = f2bf(a.y); o[2] = f2bf(a.z); o[3] = f2bf(a.w);
  o[4] = f2bf(b.x); o[5] = f2bf(b.y); o[6] = f2bf(b.z); o[7] = f2bf(b.w);
  ((u16x8*)dst)[j] = o;
}

// C[z][m,n] = epi( scale * sum_k A[z][m,k] * B[z][n,k] )
// EPI: 0 plain; 1 exp + fused row-sum (shfl + atomicAdd into rs); 2 div by rs.
// bf16 in, OT out, fp32 accum. 256 thr (2x2 waves), tile 128x128, BK=64
// (m97 recipe: 32 MFMAs per barrier pair, 32 KB LDS), MFMA 16x16x32 bf16
// (16 independent acc chains/wave -- the ILP that 32x32 lacked, see R4).
template <typename OT, int EPI>
__global__ __launch_bounds__(256) void gemm_bt(
    const u16* __restrict__ A, int lda, long zsA,
    const u16* __restrict__ B, int ldb, long zsB,
    OT* __restrict__ C, int ldc, long zsC,
    int K, float scale, float* __restrict__ rs) {
  const int z = blockIdx.z;
  A += (long)z * zsA;
  B += (long)z * zsB;
  C += (long)z * zsC;
  if constexpr (EPI != 0) rs += (long)z * 4096;  // batch-local rows, S = 4096

  __shared__ __align__(16) u16 As[2 * 128 * 32];  // [s][row][32k]
  __shared__ __align__(16) u16 Bs[2 * 128 * 32];
  const int tid  = threadIdx.x;
  const int m0   = blockIdx.y * 128;
  const int n0   = blockIdx.x * 128;
  const int wave = tid >> 6;
  const int lane = tid & 63;
  const int wm   = (wave >> 1) * 64;
  const int wn   = (wave & 1) * 64;
  const int l15  = lane & 15;
  const int quad = lane >> 4;

  f32x4 acc[4][4];
#pragma unroll
  for (int i = 0; i < 4; ++i)
#pragma unroll
    for (int j = 0; j < 4; ++j) acc[i][j] = f32x4{0.f, 0.f, 0.f, 0.f};

  // Staging: per stage s, tile row-major [128][32]. Thread t's 16B chunk:
  // row = t>>2 (+64), col = (t&3)*8. Lane-contiguous LDS dests.
  const u16* gA0 = A + (size_t)(m0 + (tid >> 2)) * lda + (tid & 3) * 8;
  const u16* gA1 = A + (size_t)(m0 + 64 + (tid >> 2)) * lda + (tid & 3) * 8;
  const u16* gB0 = B + (size_t)(n0 + (tid >> 2)) * ldb + (tid & 3) * 8;
  const u16* gB1 = B + (size_t)(n0 + 64 + (tid >> 2)) * ldb + (tid & 3) * 8;
  u16* lA0 = As + tid * 8;
  u16* lA1 = As + (256 + tid) * 8;
  u16* lB0 = Bs + tid * 8;
  u16* lB1 = Bs + (256 + tid) * 8;

  for (int k0 = 0; k0 < K; k0 += 64) {
    __syncthreads();  // previous iter's LDS reads done before overwrite
#pragma unroll
    for (int s = 0; s < 2; ++s) {
      gload_lds16(gA0 + k0 + s * 32, lA0 + s * 4096);
      gload_lds16(gA1 + k0 + s * 32, lA1 + s * 4096);
      gload_lds16(gB0 + k0 + s * 32, lB0 + s * 4096);
      gload_lds16(gB1 + k0 + s * 32, lB1 + s * 4096);
    }
    __syncthreads();  // staging landed

#pragma unroll
    for (int s = 0; s < 2; ++s) {
      u16x8 a[4], b[4];
#pragma unroll
      for (int i = 0; i < 4; ++i)
        a[i] = *(const u16x8*)(As + s * 4096 + (wm + i * 16 + l15) * 32 + quad * 8);
#pragma unroll
      for (int j = 0; j < 4; ++j)
        b[j] = *(const u16x8*)(Bs + s * 4096 + (wn + j * 16 + l15) * 32 + quad * 8);
#pragma unroll
      for (int i = 0; i < 4; ++i)
#pragma unroll
        for (int j = 0; j < 4; ++j)
          acc[i][j] = __builtin_amdgcn_mfma_f32_16x16x32_bf16(
              __builtin_bit_cast(bf16x8, a[i]), __builtin_bit_cast(bf16x8, b[j]),
              acc[i][j], 0, 0, 0);
    }
  }

  // C/D layout (m89-verified): col = lane&15, row = (lane>>4)*4 + reg
#pragma unroll
  for (int i = 0; i < 4; ++i) {
#pragma unroll
    for (int r = 0; r < 4; ++r) {
      const int row = m0 + wm + i * 16 + quad * 4 + r;
      float mul = scale;
      if constexpr (EPI == 2) mul = scale / rs[row];
      const size_t ro = (size_t)row * ldc;
      float vj[4];
#pragma unroll
      for (int j = 0; j < 4; ++j) {
        float v = acc[i][j][r] * mul;
        if constexpr (EPI == 1) v = __expf(v);
        vj[j] = v;
        const int col = n0 + wn + j * 16 + l15;
        if constexpr (__is_same(OT, float))
          C[ro + col] = v;
        else
          C[ro + col] = f2bf(v);
      }
      if constexpr (EPI == 1) {
        // row sum of this wave's 64-col stripe: in-lane over j, then over the
        // 16 lanes of the quad (shfl_xor bits 0-3), atomic from l15==0.
        float ps = (vj[0] + vj[1]) + (vj[2] + vj[3]);
#pragma unroll
        for (int o = 1; o <= 8; o <<= 1) ps += __shfl_xor(ps, o, 64);
        if (l15 == 0) atomicAdd(&rs[row], ps);
      }
    }
  }
}

// Vt[z][d, s] = V[z][s, d].
__global__ __launch_bounds__(256) void transpose_v(
    const u16* __restrict__ V, int ldv, long zsV,
    u16* __restrict__ Vt, int ldt, long zsT) {
  const int z = blockIdx.z;
  V  += (long)z * zsV;
  Vt += (long)z * zsT;
  __shared__ u16 T[64][65];
  const int d0 = blockIdx.x * 64;
  const int s0 = blockIdx.y * 64;
  const int tid = threadIdx.x;
  const int c = tid & 63;
  const int rbase = (tid >> 6) * 16;
#pragma unroll
  for (int r = 0; r < 16; ++r)
    T[rbase + r][c] = V[(size_t)(s0 + rbase + r) * ldv + d0 + c];
  __syncthreads();
#pragma unroll
  for (int r = 0; r < 16; ++r)
    Vt[(size_t)(d0 + rbase + r) * ldt + s0 + c] = T[c][rbase + r];
}

extern "C" void kernel_launch(void* const* d_in, const int* in_sizes, int n_in,
                              void* d_out, int out_size, void* d_ws, size_t ws_size,
                              hipStream_t stream) {
  const float* x    = (const float*)d_in[0];  // [B*S, D] fp32
  const float* Wqkv = (const float*)d_in[1];  // [3D, D]  fp32
  const float* Wo   = (const float*)d_in[2];  // [D, D]   fp32
  float* out = (float*)d_out;                 // [B*S, D] fp32

  const int Bn = 4, S = 4096, D = 1024;
  const int M = Bn * S;  // 16384
  const int E = 3 * D;   // 3072
  const long SE = (long)S * E, SS = (long)S * S, DS = (long)D * S, SD = (long)S * D;

  const size_t need4 = 310378496;  // 296 MB -> batched grid.z=4 path
  const int nb = (ws_size >= need4) ? 4 : 1;

  char* ws = (char*)d_ws;
  size_t off = 0;
  u16* qkv = (u16*)(ws + off);  off += (size_t)M * E * 2;        // 96 MB
  u16* Sb  = (u16*)(ws + off);  off += (size_t)nb * S * S * 2;   // nb*32 MB
  u16* Vt  = (u16*)(ws + off);  off += (size_t)nb * D * S * 2;   // nb*8 MB
  u16* xb  = (u16*)(ws + off);  off += (size_t)M * D * 2;        // 32 MB
  u16* attn = xb;                 // xb dead after QKV proj
  u16* Wqkvb = (u16*)(ws + off); off += (size_t)E * D * 2;       // 6 MB
  u16* Wob   = (u16*)(ws + off); off += (size_t)D * D * 2;       // 2 MB
  // rowsum [nb][4096] fp32 aliases Wqkvb (dead after QKV gemm; memset after).
  float* rs = (float*)Wqkvb;

  // 0) fp32 -> bf16 converts (fused)
  const int n1 = M * D / 8, n2 = E * D / 8, n3 = D * D / 8;
  cvt_all<<<(n1 + n2 + n3 + 255) / 256, 256, 0, stream>>>(
      x, Wqkv, Wo, xb, Wqkvb, Wob, n1, n2, n3);

  // 1) QKV projection: qkv = xb @ Wqkvb^T   [16384 x 3072]
  gemm_bt<u16, 0><<<dim3(E / 128, M / 128, 1), 256, 0, stream>>>(
      xb, D, 0, Wqkvb, D, 0, qkv, E, 0, D, 1.0f, nullptr);

  const float scl = 0.03125f;  // 1/sqrt(1024)
  if (nb == 4) {
    hipMemsetAsync(rs, 0, (size_t)4 * S * sizeof(float), stream);
    // 2) P = exp(Q K^T / 32) unnormalized; fused row-sums -> rs (atomics)
    gemm_bt<u16, 1><<<dim3(S / 128, S / 128, 4), 256, 0, stream>>>(
        qkv, E, SE, qkv + D, E, SE, Sb, S, SS, D, scl, rs);
    // 3) Vt = V^T
    transpose_v<<<dim3(D / 64, S / 64, 4), 256, 0, stream>>>(
        qkv + 2 * D, E, SE, Vt, S, DS);
    // 4) attn = (P @ V) / rs
    gemm_bt<u16, 2><<<dim3(D / 128, S / 128, 4), 256, 0, stream>>>(
        Sb, S, SS, Vt, S, DS, attn, D, SD, S, 1.0f, rs);
  } else {
    for (int b = 0; b < Bn; ++b) {
      const u16* Qb = qkv + (size_t)b * SE;
      hipMemsetAsync(rs, 0, (size_t)S * sizeof(float), stream);
      gemm_bt<u16, 1><<<dim3(S / 128, S / 128, 1), 256, 0, stream>>>(
          Qb, E, 0, Qb + D, E, 0, Sb, S, 0, D, scl, rs);
      transpose_v<<<dim3(D / 64, S / 64, 1), 256, 0, stream>>>(
          Qb + 2 * D, E, 0, Vt, S, 0);
      gemm_bt<u16, 2><<<dim3(D / 128, S / 128, 1), 256, 0, stream>>>(
          Sb, S, 0, Vt, S, 0, attn + (size_t)b * SD, D, 0, S, 1.0f, rs);
    }
  }
  // 5) out = attn @ Wo^T  [16384 x 1024] -> fp32
  gemm_bt<float, 0><<<dim3(D / 128, M / 128, 1), 256, 0, stream>>>(
      attn, D, 0, Wob, D, 0, out, D, 0, D, 1.0f, nullptr);
}

// Round 6
// 699.302 us; speedup vs baseline: 1.3132x; 1.2503x over previous
//
#include <hip/hip_runtime.h>
#include <hip/hip_bf16.h>
#include <stdint.h>

typedef unsigned short u16;
typedef __bf16 bf16x8 __attribute__((ext_vector_type(8)));
typedef unsigned short u16x8 __attribute__((ext_vector_type(8)));
typedef float f32x4 __attribute__((ext_vector_type(4)));

__device__ __forceinline__ float bf2f(u16 h) {
  union { uint32_t u; float f; } x;
  x.u = ((uint32_t)h) << 16;
  return x.f;
}
__device__ __forceinline__ u16 f2bf(float f) {
  union { float f; uint32_t u; } x;
  x.f = f;
  uint32_t r = x.u + 0x7FFFu + ((x.u >> 16) & 1u);  // round-to-nearest-even
  return (u16)(r >> 16);
}

// async global->LDS, 16B per lane. LDS dest must be wave-uniform base + lane*16.
__device__ __forceinline__ void gload_lds16(const u16* g, u16* l) {
  __builtin_amdgcn_global_load_lds(
      (const __attribute__((address_space(1))) uint32_t*)g,
      (__attribute__((address_space(3))) uint32_t*)l, 16, 0, 0);
}

// One fused fp32->bf16 convert for x, W_qkv, W_o. Counts are 8-elem chunks.
__global__ __launch_bounds__(256) void cvt_all(
    const float* __restrict__ x, const float* __restrict__ w1,
    const float* __restrict__ w2, u16* __restrict__ xb,
    u16* __restrict__ w1b, u16* __restrict__ w2b, int n1, int n2, int n3) {
  int i = blockIdx.x * 256 + threadIdx.x;
  const float* src;
  u16* dst;
  int j = i;
  if (i < n1) { src = x; dst = xb; }
  else if (i < n1 + n2) { src = w1; dst = w1b; j = i - n1; }
  else if (i < n1 + n2 + n3) { src = w2; dst = w2b; j = i - n1 - n2; }
  else return;
  const float4* p = (const float4*)src + (size_t)j * 2;
  float4 a = p[0], b = p[1];
  u16x8 o;
  o[0] = f2bf(a.x); o[1] = f2bf(a.y); o[2] = f2bf(a.z); o[3] = f2bf(a.w);
  o[4] = f2bf(b.x); o[5] = f2bf(b.y); o[6] = f2bf(b.z); o[7] = f2bf(b.w);
  ((u16x8*)dst)[j] = o;
}

// C[z][m,n] = epi( scale * sum_k A[z][m,k] * B[z][n,k] )
// EPI: 0 plain; 1 exp (unnormalized softmax); 2 divide by rs[z*4096+row].
// bf16 in, OT out, fp32 accum. 256 thr (2x2 waves), tile 128x128, BK=64
// (m97 recipe: 32 MFMAs per barrier pair, 32 KB LDS), MFMA 16x16x32 bf16
// (16 independent acc chains/wave -- the ILP that 32x32 lacked, R4).
// NO fused row-reduction: shfl+atomic epilogue measured slower than a
// separate BW-bound rowsum pass (R5).
template <typename OT, int EPI>
__global__ __launch_bounds__(256) void gemm_bt(
    const u16* __restrict__ A, int lda, long zsA,
    const u16* __restrict__ B, int ldb, long zsB,
    OT* __restrict__ C, int ldc, long zsC,
    int K, float scale, const float* __restrict__ rs) {
  const int z = blockIdx.z;
  A += (long)z * zsA;
  B += (long)z * zsB;
  C += (long)z * zsC;
  if constexpr (EPI == 2) rs += (long)z * 4096;  // batch-local rows, S = 4096

  __shared__ __align__(16) u16 As[2 * 128 * 32];  // [s][row][32k]
  __shared__ __align__(16) u16 Bs[2 * 128 * 32];
  const int tid  = threadIdx.x;
  const int m0   = blockIdx.y * 128;
  const int n0   = blockIdx.x * 128;
  const int wave = tid >> 6;
  const int lane = tid & 63;
  const int wm   = (wave >> 1) * 64;
  const int wn   = (wave & 1) * 64;
  const int l15  = lane & 15;
  const int quad = lane >> 4;

  f32x4 acc[4][4];
#pragma unroll
  for (int i = 0; i < 4; ++i)
#pragma unroll
    for (int j = 0; j < 4; ++j) acc[i][j] = f32x4{0.f, 0.f, 0.f, 0.f};

  // Staging: per stage s, tile row-major [128][32]. Thread t's 16B chunk:
  // row = t>>2 (+64), col = (t&3)*8. Lane-contiguous LDS dests.
  const u16* gA0 = A + (size_t)(m0 + (tid >> 2)) * lda + (tid & 3) * 8;
  const u16* gA1 = A + (size_t)(m0 + 64 + (tid >> 2)) * lda + (tid & 3) * 8;
  const u16* gB0 = B + (size_t)(n0 + (tid >> 2)) * ldb + (tid & 3) * 8;
  const u16* gB1 = B + (size_t)(n0 + 64 + (tid >> 2)) * ldb + (tid & 3) * 8;
  u16* lA0 = As + tid * 8;
  u16* lA1 = As + (256 + tid) * 8;
  u16* lB0 = Bs + tid * 8;
  u16* lB1 = Bs + (256 + tid) * 8;

  for (int k0 = 0; k0 < K; k0 += 64) {
    __syncthreads();  // previous iter's LDS reads done before overwrite
#pragma unroll
    for (int s = 0; s < 2; ++s) {
      gload_lds16(gA0 + k0 + s * 32, lA0 + s * 4096);
      gload_lds16(gA1 + k0 + s * 32, lA1 + s * 4096);
      gload_lds16(gB0 + k0 + s * 32, lB0 + s * 4096);
      gload_lds16(gB1 + k0 + s * 32, lB1 + s * 4096);
    }
    __syncthreads();  // staging landed

#pragma unroll
    for (int s = 0; s < 2; ++s) {
      u16x8 a[4], b[4];
#pragma unroll
      for (int i = 0; i < 4; ++i)
        a[i] = *(const u16x8*)(As + s * 4096 + (wm + i * 16 + l15) * 32 + quad * 8);
#pragma unroll
      for (int j = 0; j < 4; ++j)
        b[j] = *(const u16x8*)(Bs + s * 4096 + (wn + j * 16 + l15) * 32 + quad * 8);
#pragma unroll
      for (int i = 0; i < 4; ++i)
#pragma unroll
        for (int j = 0; j < 4; ++j)
          acc[i][j] = __builtin_amdgcn_mfma_f32_16x16x32_bf16(
              __builtin_bit_cast(bf16x8, a[i]), __builtin_bit_cast(bf16x8, b[j]),
              acc[i][j], 0, 0, 0);
    }
  }

  // C/D layout (m89-verified): col = lane&15, row = (lane>>4)*4 + reg
#pragma unroll
  for (int i = 0; i < 4; ++i) {
#pragma unroll
    for (int r = 0; r < 4; ++r) {
      const int row = m0 + wm + i * 16 + quad * 4 + r;
      float mul = scale;
      if constexpr (EPI == 2) mul = scale / rs[row];
      const size_t ro = (size_t)row * ldc;
#pragma unroll
      for (int j = 0; j < 4; ++j) {
        float v = acc[i][j][r] * mul;
        if constexpr (EPI == 1) v = __expf(v);
        const int col = n0 + wn + j * 16 + l15;
        if constexpr (__is_same(OT, float))
          C[ro + col] = v;
        else
          C[ro + col] = f2bf(v);
      }
    }
  }
}

// rs[z*4096+row] = sum over 4096 cols of P[z][row][*] (bf16). Direct write.
__global__ __launch_bounds__(256) void rowsum_rows(
    const u16* __restrict__ P, long zsP, float* __restrict__ rs) {
  const int row = blockIdx.x;
  const int z   = blockIdx.y;
  const u16* p = P + (long)z * zsP + (size_t)row * 4096;
  const int tid  = threadIdx.x;
  const int lane = tid & 63;
  const int wave = tid >> 6;

  u16x8 h0 = *(const u16x8*)(p + tid * 16);
  u16x8 h1 = *(const u16x8*)(p + tid * 16 + 8);
  float s = 0.f;
#pragma unroll
  for (int j = 0; j < 8; ++j) s += bf2f(h0[j]) + bf2f(h1[j]);
  for (int o = 32; o > 0; o >>= 1) s += __shfl_xor(s, o, 64);
  __shared__ float red[4];
  if (lane == 0) red[wave] = s;
  __syncthreads();
  if (tid == 0) rs[(size_t)z * 4096 + row] = red[0] + red[1] + red[2] + red[3];
}

// Vt[z][d, s] = V[z][s, d].
__global__ __launch_bounds__(256) void transpose_v(
    const u16* __restrict__ V, int ldv, long zsV,
    u16* __restrict__ Vt, int ldt, long zsT) {
  const int z = blockIdx.z;
  V  += (long)z * zsV;
  Vt += (long)z * zsT;
  __shared__ u16 T[64][65];
  const int d0 = blockIdx.x * 64;
  const int s0 = blockIdx.y * 64;
  const int tid = threadIdx.x;
  const int c = tid & 63;
  const int rbase = (tid >> 6) * 16;
#pragma unroll
  for (int r = 0; r < 16; ++r)
    T[rbase + r][c] = V[(size_t)(s0 + rbase + r) * ldv + d0 + c];
  __syncthreads();
#pragma unroll
  for (int r = 0; r < 16; ++r)
    Vt[(size_t)(d0 + rbase + r) * ldt + s0 + c] = T[c][rbase + r];
}

extern "C" void kernel_launch(void* const* d_in, const int* in_sizes, int n_in,
                              void* d_out, int out_size, void* d_ws, size_t ws_size,
                              hipStream_t stream) {
  const float* x    = (const float*)d_in[0];  // [B*S, D] fp32
  const float* Wqkv = (const float*)d_in[1];  // [3D, D]  fp32
  const float* Wo   = (const float*)d_in[2];  // [D, D]   fp32
  float* out = (float*)d_out;                 // [B*S, D] fp32

  const int Bn = 4, S = 4096, D = 1024;
  const int M = Bn * S;  // 16384
  const int E = 3 * D;   // 3072
  const long SE = (long)S * E, SS = (long)S * S, DS = (long)D * S, SD = (long)S * D;

  // Chunked path (2 batches per dispatch wave) needs:
  // qkv 96 + Sb 64 + Vt 16 + xb/attn 32 + W 8 = 216 MB. Known ws >= 176 MB
  // (R2 ran the 176 MB layout). Gate is call-invariant (ws_size fixed).
  const int nz = (ws_size >= (size_t)226492416) ? 2 : 1;  // 216 MB

  char* ws = (char*)d_ws;
  size_t off = 0;
  u16* qkv = (u16*)(ws + off);  off += (size_t)M * E * 2;        // 96 MB
  u16* Sb  = (u16*)(ws + off);  off += (size_t)nz * S * S * 2;   // nz*32 MB
  u16* Vt  = (u16*)(ws + off);  off += (size_t)nz * D * S * 2;   // nz*8 MB
  u16* xb  = (u16*)(ws + off);  off += (size_t)M * D * 2;        // 32 MB
  u16* attn = xb;                 // xb dead after QKV proj
  u16* Wqkvb = (u16*)(ws + off); off += (size_t)E * D * 2;       // 6 MB
  u16* Wob   = (u16*)(ws + off); off += (size_t)D * D * 2;       // 2 MB
  // rowsum [nz][4096] fp32 aliases Wqkvb (dead after QKV gemm; rowsum_rows
  // direct-writes it before PV reads it). 32 KB.
  float* rs = (float*)Wqkvb;

  // 0) fp32 -> bf16 converts (fused)
  const int n1 = M * D / 8, n2 = E * D / 8, n3 = D * D / 8;
  cvt_all<<<(n1 + n2 + n3 + 255) / 256, 256, 0, stream>>>(
      x, Wqkv, Wo, xb, Wqkvb, Wob, n1, n2, n3);

  // 1) QKV projection: qkv = xb @ Wqkvb^T   [16384 x 3072]
  gemm_bt<u16, 0><<<dim3(E / 128, M / 128, 1), 256, 0, stream>>>(
      xb, D, 0, Wqkvb, D, 0, qkv, E, 0, D, 1.0f, nullptr);

  const float scl = 0.03125f;  // 1/sqrt(1024)
  // Per chunk of nz batches: transpose V, P=exp(QK^T/32), rowsum, PV/rs.
  for (int c = 0; c < Bn; c += nz) {
    const u16* Qc = qkv + (size_t)c * SE;
    transpose_v<<<dim3(D / 64, S / 64, nz), 256, 0, stream>>>(
        Qc + 2 * D, E, SE, Vt, S, DS);
    gemm_bt<u16, 1><<<dim3(S / 128, S / 128, nz), 256, 0, stream>>>(
        Qc, E, SE, Qc + D, E, SE, Sb, S, SS, D, scl, nullptr);
    rowsum_rows<<<dim3(S, nz), 256, 0, stream>>>(Sb, SS, rs);
    gemm_bt<u16, 2><<<dim3(D / 128, S / 128, nz), 256, 0, stream>>>(
        Sb, S, SS, Vt, S, DS, attn + (size_t)c * SD, D, SD, S, 1.0f, rs);
  }

  // 2) out = attn @ Wo^T  [16384 x 1024] -> fp32
  gemm_bt<float, 0><<<dim3(D / 128, M / 128, 1), 256, 0, stream>>>(
      attn, D, 0, Wob, D, 0, out, D, 0, D, 1.0f, nullptr);
}